// Round 2
// baseline (2786.064 us; speedup 1.0000x reference)
//
#include <hip/hip_runtime.h>
#include <math.h>

// Problem constants (fixed by reference)
#define B 128
#define R 36
#define VIS 2048
#define MM 1024
#define E 512
#define ATT 512
#define D 1024
#define V 10000
#define MAXLEN 20
#define T 19          // MAXLEN - 1
#define G4 4096       // 4*D
#define NBLK_REC 256  // persistent kernel grid (== #CUs, co-residency safe)

typedef unsigned short bf16_t;
typedef __attribute__((ext_vector_type(8))) short short8;
typedef __attribute__((ext_vector_type(4))) float f32x4;
typedef __attribute__((ext_vector_type(4))) unsigned short ushort4v;

__device__ __forceinline__ bf16_t f2bf(float f) {
    unsigned u = __float_as_uint(f);
    u += 0x7fff + ((u >> 16) & 1);   // round-to-nearest-even
    return (bf16_t)(u >> 16);
}
__device__ __forceinline__ float bf2f(bf16_t b) {
    return __uint_as_float(((unsigned)b) << 16);
}
__device__ __forceinline__ float sigmoidf_(float x) { return 1.0f / (1.0f + expf(-x)); }

// Async global->LDS, 16B per lane. LDS dest = wave-uniform base + lane*16.
__device__ __forceinline__ void stage16(const bf16_t* g, bf16_t* lds_wave_base, int lane) {
#if defined(__has_builtin) && __has_builtin(__builtin_amdgcn_global_load_lds)
    __builtin_amdgcn_global_load_lds(
        (const __attribute__((address_space(1))) void*)g,
        (__attribute__((address_space(3))) void*)lds_wave_base, 16, 0, 0);
#else
    *(short8*)(lds_wave_base + lane * 8) = *(const short8*)g;
#endif
}

// Device-scope sense(epoch) grid barrier. cnt at bar[0], gen at bar[32]
// (separate cachelines). Entry __syncthreads drains each thread's stores
// (vmcnt) before tid0's agent fence (buffer_wbl2) makes them XCD-visible.
__device__ __forceinline__ void gridbar(int* bar) {
    __syncthreads();
    if (threadIdx.x == 0) {
        __threadfence();   // release: flush this XCD's L2
        int gen = __hip_atomic_load(&bar[32], __ATOMIC_RELAXED, __HIP_MEMORY_SCOPE_AGENT);
        int arr = __hip_atomic_fetch_add(&bar[0], 1, __ATOMIC_ACQ_REL, __HIP_MEMORY_SCOPE_AGENT);
        if (arr == NBLK_REC - 1) {
            __hip_atomic_store(&bar[0], 0, __ATOMIC_RELAXED, __HIP_MEMORY_SCOPE_AGENT);
            __hip_atomic_fetch_add(&bar[32], 1, __ATOMIC_RELEASE, __HIP_MEMORY_SCOPE_AGENT);
        } else {
            while (__hip_atomic_load(&bar[32], __ATOMIC_ACQUIRE, __HIP_MEMORY_SCOPE_AGENT) == gen)
                __builtin_amdgcn_s_sleep(2);
        }
        __threadfence();   // acquire: invalidate stale lines
    }
    __syncthreads();
}

// ---------------------------------------------------------------------------
// 128x128-tile bf16 MFMA GEMM, m97 structure.
// MODE 0: C[m*ldc+n] = acc (+bias)               (fp32 out)
// MODE 2: vocab projection. Grid: x = n-tile (padded to 80 = 0 mod 8 so the
//         XCD assignment n%8 is STABLE across m-groups -> each XCD keeps a
//         2.5MB Wout slice L2-resident instead of all XCDs re-fetching all
//         of Wout: FETCH 146MB -> ~65MB), y = m-tile (= timestep).
//         lengths sorted desc => valid rows are prefix [0,cnt); skip fully
//         masked 16-row fragments, wave-interleaved (rt = fm*2+wm).
// MODE 3: bf16 out: ((bf16*)C)[m*ldc+n] = bf16(acc)
// ---------------------------------------------------------------------------
template<int MODE>
__global__ __launch_bounds__(256) void mfma_gemm_lds(
    const bf16_t* __restrict__ A, const bf16_t* __restrict__ W,
    const float* __restrict__ bias, const int* __restrict__ lengths,
    float* __restrict__ C, int M, int N, int K, int ldc)
{
    __shared__ __align__(16) bf16_t As[128 * 32];
    __shared__ __align__(16) bf16_t Ws[128 * 32];
    const int tid = threadIdx.x;
    const int wave = tid >> 6, lane = tid & 63;
    const int wm = wave >> 1, wn = wave & 1;
    const int quad = lane >> 4, l16 = lane & 15;
    const int m0 = blockIdx.y * 128;
    const int n0 = blockIdx.x * 128;
    if (MODE == 2 && n0 >= N) return;        // grid.x padded to multiple of 8

    int cnt = 128;
    if constexpr (MODE == 2) {
        const int tt = blockIdx.y;           // m-tile == timestep (B==128)
        cnt = __syncthreads_count(tid < B && lengths[tid] > tt);
    }

    f32x4 acc[4][4];
    #pragma unroll
    for (int i = 0; i < 4; ++i)
        #pragma unroll
        for (int j = 0; j < 4; ++j)
            acc[i][j] = (f32x4){0.f, 0.f, 0.f, 0.f};

    for (int kk = 0; kk < K; kk += 32) {
        #pragma unroll
        for (int i = 0; i < 2; ++i) {
            int c = tid + i * 256;          // chunk 0..511
            int row = c >> 2, seg = c & 3;
            int m = m0 + row; if (m >= M) m = M - 1;
            stage16(A + (size_t)m * K + kk + seg * 8, &As[(i * 256 + wave * 64) * 8], lane);
            int n = n0 + row; if (n >= N) n = N - 1;
            stage16(W + (size_t)n * K + kk + seg * 8, &Ws[(i * 256 + wave * 64) * 8], lane);
        }
        __syncthreads();
        short8 af[4], bfr[4];
        #pragma unroll
        for (int fm = 0; fm < 4; ++fm) {
            const int rt = (MODE == 2) ? fm * 2 + wm : wm * 4 + fm;
            if (MODE != 2 || rt * 16 < cnt)
                af[fm] = *(const short8*)&As[(rt * 16 + l16) * 32 + quad * 8];
        }
        #pragma unroll
        for (int fn = 0; fn < 4; ++fn)
            bfr[fn] = *(const short8*)&Ws[(wn * 64 + fn * 16 + l16) * 32 + quad * 8];
        #pragma unroll
        for (int fm = 0; fm < 4; ++fm) {
            const int rt = (MODE == 2) ? fm * 2 + wm : wm * 4 + fm;
            if (MODE == 2 && rt * 16 >= cnt) continue;
            #pragma unroll
            for (int fn = 0; fn < 4; ++fn)
                acc[fm][fn] = __builtin_amdgcn_mfma_f32_16x16x32_bf16(
                    af[fm], bfr[fn], acc[fm][fn], 0, 0, 0);
        }
        __syncthreads();
    }

    #pragma unroll
    for (int fm = 0; fm < 4; ++fm) {
        const int rt = (MODE == 2) ? fm * 2 + wm : wm * 4 + fm;
        #pragma unroll
        for (int fn = 0; fn < 4; ++fn) {
            #pragma unroll
            for (int r = 0; r < 4; ++r) {
                int m = m0 + rt * 16 + quad * 4 + r;
                int n = n0 + wn * 64 + fn * 16 + l16;
                if (m >= M || n >= N) continue;
                float v = acc[fm][fn][r];
                if (MODE == 0) {
                    if (bias) v += bias[n];
                    C[(size_t)m * ldc + n] = v;
                } else if (MODE == 2) {
                    int t = m >> 7, b = m & 127;
                    v = (t < lengths[b]) ? (v + bias[n]) : 0.f;
                    C[((size_t)b * T + t) * V + n] = v;
                } else {
                    ((bf16_t*)C)[(size_t)m * ldc + n] = f2bf(v);
                }
            }
        }
    }
}

// ---------------------------------------------------------------------------
// Persistent recurrence kernel: all T steps in ONE dispatch.
// Grid 256 blocks x 256 threads (1/CU; LDS 70KB => capacity >= 2/CU, so all
// blocks are co-resident regardless of packing -> grid barrier is safe).
//
// Per step:
//   ATT phase : block pair (b = blk>>1, half = blk&1). Both compute alpha
//               (redundant, cheap), each contracts its 2048-col half of
//               partial[b] = sum_r alpha*P[b,r,:] + wordsW[t,b,:].
//               GEMV ah = Wh@h is 16-lanes-per-row (coalesced 256B reads,
//               __shfl_xor reduce) -- old one-thread-per-row was 4x
//               over-fetching L2.
//   gridbar
//   GATE phase: block (d0 = (blk&127)*8, m0 = (blk>>7)*64). Whh slab (64KB)
//               staged to LDS ONCE in the prologue (was re-staged 19x);
//               biases/lengths live in registers across steps.
//   gridbar (skipped on last step)
// ---------------------------------------------------------------------------
__global__ __launch_bounds__(256) void recurrence_k(
    const bf16_t* __restrict__ Whh,
    const bf16_t* __restrict__ Wh_bf,
    const float* __restrict__ att_fea,
    const float* __restrict__ att_bias,
    const float* __restrict__ Ww,
    const bf16_t* __restrict__ P_bf,
    const float* __restrict__ wordsW,
    const float* __restrict__ bih,
    const float* __restrict__ bhh,
    const int* __restrict__ lengths,
    float* __restrict__ partial,
    float* __restrict__ hf,
    float* __restrict__ c_st,
    bf16_t* __restrict__ h_p0,
    bf16_t* __restrict__ h_p1,
    bf16_t* __restrict__ hseq,
    int* bar)
{
    __shared__ __align__(16) bf16_t Ws[32 * 1024];   // 64 KB, persists all steps
    __shared__ float hs[D];
    __shared__ float ah_s[ATT];
    __shared__ float sc_s[64];
    __shared__ float alpha_s[R];

    const int tid = threadIdx.x;
    const int blk = blockIdx.x;
    const int wave = tid >> 6, lane = tid & 63;
    const int quad = lane >> 4, l16 = lane & 15;

    // gates mapping
    const int d0 = (blk & 127) * 8;
    const int m0 = (blk >> 7) * 64;
    const int gsel_ = l16 >> 3, dr = l16 & 7;
    // attention mapping
    const int ab = blk >> 1, ahalf = blk & 1;

    // ---- one-shot Whh slab staging (layout: [qk 0..127][row 0..31][8]) ----
    #pragma unroll
    for (int i = 0; i < 16; ++i) {
        int c = i * 256 + tid;               // chunk 0..4095
        int row = c & 31, qk = c >> 5;
        int rv = (row >> 3) * D + d0 + (row & 7);
        stage16(Whh + (size_t)rv * D + qk * 8, &Ws[(i * 256 + wave * 64) * 8], lane);
    }
    // per-thread invariants
    const int d = d0 + dr;
    const int col0 = gsel_ * D + d;
    const int col1 = (2 + gsel_) * D + d;
    const float bia0 = bih[col0] + bhh[col0];
    const float bia1 = bih[col1] + bhh[col1];
    int len_m[4];
    #pragma unroll
    for (int r = 0; r < 4; ++r) len_m[r] = lengths[m0 + wave * 16 + quad * 4 + r];

    bf16_t* hbuf[2] = { h_p0, h_p1 };

    for (int t = 0; t < T; ++t) {
        // ================= attention phase =================
        if (t > 0) {
            ((float4*)hs)[tid] = ((const float4*)(hf + (size_t)ab * D))[tid];
            __syncthreads();
            // ah = Wh @ h : 16 lanes per row (sub = k-chunk, quad = row-in-group)
            const int sub = l16;
            #pragma unroll 4
            for (int pass = 0; pass < 32; ++pass) {
                int a = wave * 128 + pass * 4 + quad;
                const bf16_t* wrow = Wh_bf + (size_t)a * D + sub * 8;
                float s = 0.f;
                #pragma unroll
                for (int kc = 0; kc < 8; ++kc) {
                    short8 wv = *(const short8*)(wrow + kc * 128);
                    const float* hp = &hs[kc * 128 + sub * 8];
                    float4 hA = *(const float4*)hp;
                    float4 hB = *(const float4*)(hp + 4);
                    s = fmaf(bf2f((bf16_t)wv[0]), hA.x, s);
                    s = fmaf(bf2f((bf16_t)wv[1]), hA.y, s);
                    s = fmaf(bf2f((bf16_t)wv[2]), hA.z, s);
                    s = fmaf(bf2f((bf16_t)wv[3]), hA.w, s);
                    s = fmaf(bf2f((bf16_t)wv[4]), hB.x, s);
                    s = fmaf(bf2f((bf16_t)wv[5]), hB.y, s);
                    s = fmaf(bf2f((bf16_t)wv[6]), hB.z, s);
                    s = fmaf(bf2f((bf16_t)wv[7]), hB.w, s);
                }
                s += __shfl_xor(s, 1); s += __shfl_xor(s, 2);
                s += __shfl_xor(s, 4); s += __shfl_xor(s, 8);
                if (sub == 0) ah_s[a] = s;
            }
            __syncthreads();
            // scores
            for (int r = wave; r < R; r += 4) {
                float abv = att_bias[r];
                const float* af = att_fea + ((size_t)ab * R + r) * ATT;
                float s = 0.f;
                for (int a = lane; a < ATT; a += 64) {
                    float v = af[a] + ah_s[a] + abv;
                    s = fmaf(fmaxf(v, 0.f), Ww[a], s);
                }
                #pragma unroll
                for (int off = 32; off; off >>= 1) s += __shfl_down(s, off);
                if (lane == 0) sc_s[r] = s;
            }
            __syncthreads();
            // softmax over R=36
            if (tid < 64) {
                float v = (tid < R) ? sc_s[tid] : -INFINITY;
                float m = v;
                #pragma unroll
                for (int off = 32; off; off >>= 1) m = fmaxf(m, __shfl_down(m, off));
                m = __shfl(m, 0);
                float e = (tid < R) ? expf(v - m) : 0.f;
                float ss = e;
                #pragma unroll
                for (int off = 32; off; off >>= 1) ss += __shfl_down(ss, off);
                ss = __shfl(ss, 0);
                if (tid < R) alpha_s[tid] = e / ss;
            }
            __syncthreads();
        }
        // contraction: this block's 2048-col half of partial[ab]
        {
            const int n0c = ahalf * 2048 + tid * 8;
            float acc[8];
            #pragma unroll
            for (int j = 0; j < 8; ++j) acc[j] = 0.f;
            const bf16_t* Pb = P_bf + (size_t)ab * R * G4 + n0c;
            #pragma unroll 4
            for (int r = 0; r < R; ++r) {
                float al = (t == 0) ? (1.0f / R) : alpha_s[r];
                short8 p = *(const short8*)(Pb + (size_t)r * G4);
                #pragma unroll
                for (int j = 0; j < 8; ++j)
                    acc[j] = fmaf(al, bf2f((bf16_t)p[j]), acc[j]);
            }
            const float* wsl = wordsW + ((size_t)t * B + ab) * G4 + n0c;
            float* po = partial + (size_t)ab * G4 + n0c;
            float4 w0 = *(const float4*)(wsl);
            float4 w1 = *(const float4*)(wsl + 4);
            float4 o0 = { acc[0] + w0.x, acc[1] + w0.y, acc[2] + w0.z, acc[3] + w0.w };
            float4 o1 = { acc[4] + w1.x, acc[5] + w1.y, acc[6] + w1.z, acc[7] + w1.w };
            *(float4*)(po)     = o0;
            *(float4*)(po + 4) = o1;
        }
        gridbar(bar);

        // ================= gates phase =================
        {
            const bf16_t* h_in = hbuf[t & 1];
            const bf16_t* Ar = h_in + (size_t)(m0 + wave * 16 + l16) * D + quad * 8;
            f32x4 acc0 = (f32x4){0.f, 0.f, 0.f, 0.f};
            f32x4 acc1 = (f32x4){0.f, 0.f, 0.f, 0.f};
            #pragma unroll 8
            for (int kt = 0; kt < 32; ++kt) {
                short8 af = *(const short8*)(Ar + kt * 32);
                const int cb = (kt * 4 + quad) * 32 * 8;
                short8 b0 = *(const short8*)&Ws[cb + l16 * 8];
                short8 b1 = *(const short8*)&Ws[cb + (16 + l16) * 8];
                acc0 = __builtin_amdgcn_mfma_f32_16x16x32_bf16(af, b0, acc0, 0, 0, 0);
                acc1 = __builtin_amdgcn_mfma_f32_16x16x32_bf16(af, b1, acc1, 0, 0, 0);
            }
            bf16_t* h_nx = hbuf[(t + 1) & 1];
            #pragma unroll
            for (int r = 0; r < 4; ++r) {
                int m = m0 + wave * 16 + quad * 4 + r;
                size_t pb = (size_t)m * G4;
                float v0 = acc0[r] + bia0 + partial[pb + col0];
                float v1 = acc1[r] + bia1 + partial[pb + col1];
                float w0 = __shfl_xor(v0, 8);
                float w1 = __shfl_xor(v1, 8);
                float iv, fv, gv, ov;
                if (gsel_ == 0) { iv = v0; gv = v1; fv = w0; ov = w1; }
                else            { fv = v0; ov = v1; iv = w0; gv = w1; }
                float ig = sigmoidf_(iv), fg = sigmoidf_(fv);
                float gg = tanhf(gv),     og = sigmoidf_(ov);
                size_t off = (size_t)m * D + d;
                if (gsel_ == 0) {
                    float c_old = c_st[off];
                    float h_old = hf[off];
                    float cn = fmaf(fg, c_old, ig * gg);
                    float hn = og * tanhf(cn);
                    bool msk = t < len_m[r];
                    float cv = msk ? cn : c_old;
                    float hv = msk ? hn : h_old;
                    c_st[off] = cv;
                    hf[off] = hv;
                    bf16_t hb = f2bf(hv);
                    h_nx[off] = hb;
                    hseq[((size_t)t * B + m) * D + d] = hb;
                }
            }
        }
        if (t != T - 1) gridbar(bar);
    }
}

// Strided fp32 -> bf16 cast
__global__ __launch_bounds__(256) void cast_bf16_k(
    const float* __restrict__ src, bf16_t* __restrict__ dst,
    int rows, int cols, int ld)
{
    int idx = blockIdx.x * 256 + threadIdx.x;
    int total = rows * (cols >> 2);
    if (idx >= total) return;
    int cq = cols >> 2;
    int r = idx / cq, c4 = (idx - r * cq) * 4;
    float4 v = *(const float4*)(src + (size_t)r * ld + c4);
    ushort4v o = { f2bf(v.x), f2bf(v.y), f2bf(v.z), f2bf(v.w) };
    *(ushort4v*)(dst + (size_t)r * cols + c4) = o;
}

// words_bf[(t*B+b)*E + :] = bf16(embed_W[captions[b][t]][:])
__global__ __launch_bounds__(128) void embed_k(
    const int* __restrict__ captions, const float* __restrict__ embed_W,
    bf16_t* __restrict__ words_bf)
{
    int bt = blockIdx.x;
    int b = bt / T, t = bt - b * T;
    int tok = captions[b * MAXLEN + t];
    int i = threadIdx.x * 4;
    float4 v = *(const float4*)(embed_W + (size_t)tok * E + i);
    ushort4v o = { f2bf(v.x), f2bf(v.y), f2bf(v.z), f2bf(v.w) };
    *(ushort4v*)(words_bf + ((size_t)t * B + b) * E + i) = o;
}

extern "C" void kernel_launch(void* const* d_in, const int* in_sizes, int n_in,
                              void* d_out, int out_size, void* d_ws, size_t ws_size,
                              hipStream_t stream) {
    const float* visual   = (const float*)d_in[0];
    const float* joint    = (const float*)d_in[1];
    const int*   captions = (const int*)d_in[2];
    const int*   lengths  = (const int*)d_in[3];
    const float* embed_W  = (const float*)d_in[5];
    const float* Wih      = (const float*)d_in[6];
    const float* bih      = (const float*)d_in[7];
    const float* Whh      = (const float*)d_in[8];
    const float* bhh      = (const float*)d_in[9];
    const float* W_init_h = (const float*)d_in[10];
    const float* b_init_h = (const float*)d_in[11];
    const float* W_init_c = (const float*)d_in[12];
    const float* b_init_c = (const float*)d_in[13];
    const float* Wv       = (const float*)d_in[14];
    const float* Wh       = (const float*)d_in[15];
    const float* att_bias = (const float*)d_in[16];
    const float* Ww       = (const float*)d_in[17];
    const float* Wout     = (const float*)d_in[18];
    const float* bout     = (const float*)d_in[19];
    float* out = (float*)d_out;

    // ---- workspace carve-up ----
    char* cur = (char*)d_ws;
    auto alloc = [&](size_t bytes) { char* p = cur; cur += (bytes + 15) & ~size_t(15); return p; };
    float*  att_fea  = (float*)alloc((size_t)B * R * ATT * 4);       // 9.4 MB
    float*  wordsW   = (float*)alloc((size_t)T * B * G4 * 4);        // 39.8 MB
    float*  partial  = (float*)alloc((size_t)B * G4 * 4);            // 2.1 MB
    float*  hf       = (float*)alloc((size_t)B * D * 4);
    float*  c_st     = (float*)alloc((size_t)B * D * 4);
    bf16_t* words_bf = (bf16_t*)alloc((size_t)T * B * E * 2);
    bf16_t* h_ping0  = (bf16_t*)alloc((size_t)B * D * 2);
    bf16_t* h_ping1  = (bf16_t*)alloc((size_t)B * D * 2);
    bf16_t* hseq_bf  = (bf16_t*)alloc((size_t)T * B * D * 2);        // 5 MB
    bf16_t* P_bf     = (bf16_t*)alloc((size_t)B * R * G4 * 2);       // 37.7 MB
    bf16_t* visual_bf= (bf16_t*)alloc((size_t)B * R * VIS * 2);      // 18.9 MB
    bf16_t* Wv_bf    = (bf16_t*)alloc((size_t)ATT * VIS * 2);
    bf16_t* Wh_bf    = (bf16_t*)alloc((size_t)ATT * D * 2);
    bf16_t* Whh_bf   = (bf16_t*)alloc((size_t)G4 * D * 2);
    bf16_t* Wih_v_bf = (bf16_t*)alloc((size_t)G4 * VIS * 2);
    bf16_t* Wih_w_bf = (bf16_t*)alloc((size_t)G4 * E * 2);
    bf16_t* Wout_bf  = (bf16_t*)alloc((size_t)V * D * 2);
    bf16_t* joint_bf = (bf16_t*)alloc((size_t)B * MM * 2);
    bf16_t* Winh_bf  = (bf16_t*)alloc((size_t)D * MM * 2);
    bf16_t* Winc_bf  = (bf16_t*)alloc((size_t)D * MM * 2);
    int*    bar      = (int*)alloc(256);

    auto cast = [&](const float* s, bf16_t* dst, int rows, int cols, int ld) {
        int total = rows * (cols >> 2);
        cast_bf16_k<<<(total + 255) / 256, 256, 0, stream>>>(s, dst, rows, cols, ld);
    };
    cast(visual, visual_bf, 1, B * R * VIS, B * R * VIS);
    cast(Wv,  Wv_bf,  ATT, VIS, VIS);
    cast(Wh,  Wh_bf,  ATT, D, D);
    cast(Whh, Whh_bf, G4, D, D);
    cast(Wih, Wih_v_bf, G4, VIS, VIS + E);
    cast(Wih + VIS, Wih_w_bf, G4, E, VIS + E);
    cast(Wout, Wout_bf, V, D, D);
    cast(joint, joint_bf, 1, B * MM, B * MM);
    cast(W_init_h, Winh_bf, 1, D * MM, D * MM);
    cast(W_init_c, Winc_bf, 1, D * MM, D * MM);

    embed_k<<<B * T, 128, 0, stream>>>(captions, embed_W, words_bf);

    // h0/c0 seed via MFMA
    mfma_gemm_lds<0><<<dim3(D / 128, B / 128), 256, 0, stream>>>(
        joint_bf, Winh_bf, b_init_h, nullptr, hf, B, D, MM, D);
    mfma_gemm_lds<0><<<dim3(D / 128, B / 128), 256, 0, stream>>>(
        joint_bf, Winc_bf, b_init_c, nullptr, c_st, B, D, MM, D);
    cast(hf, h_ping0, 1, B * D, B * D);

    // att_fea = visual @ Wv^T (fp32 out)
    mfma_gemm_lds<0><<<dim3(ATT / 128, (B * R) / 128), 256, 0, stream>>>(
        visual_bf, Wv_bf, nullptr, nullptr, att_fea, B * R, ATT, VIS, ATT);

    // wordsW = words @ Wih_w^T (all steps)
    mfma_gemm_lds<0><<<dim3(G4 / 128, (T * B) / 128), 256, 0, stream>>>(
        words_bf, Wih_w_bf, nullptr, nullptr, wordsW, T * B, G4, E, G4);

    // P = visual @ Wih_v^T (bf16 out)
    mfma_gemm_lds<3><<<dim3(G4 / 128, (B * R) / 128), 256, 0, stream>>>(
        visual_bf, Wih_v_bf, nullptr, nullptr, (float*)P_bf, B * R, G4, VIS, G4);

    // ---- recurrence: ONE persistent dispatch for all T steps ----
    hipMemsetAsync(bar, 0, 256, stream);
    recurrence_k<<<NBLK_REC, 256, 0, stream>>>(
        Whh_bf, Wh_bf, att_fea, att_bias, Ww, P_bf, wordsW,
        bih, bhh, lengths, partial, hf, c_st,
        h_ping0, h_ping1, hseq_bf, bar);

    // ---- deferred vocab projection (x = n-tile padded to 80, y = m-tile) ----
    mfma_gemm_lds<2><<<dim3(80, (T * B) / 128), 256, 0, stream>>>(
        hseq_bf, Wout_bf, bout, lengths, out, T * B, V, D, V);
}

// Round 4
// 1533.764 us; speedup vs baseline: 1.8165x; 1.8165x over previous
//
#include <hip/hip_runtime.h>
#include <math.h>

// Problem constants (fixed by reference)
#define B 128
#define R 36
#define VIS 2048
#define MM 1024
#define E 512
#define ATT 512
#define D 1024
#define V 10000
#define MAXLEN 20
#define T 19          // MAXLEN - 1
#define G4 4096       // 4*D

typedef unsigned short bf16_t;
typedef __attribute__((ext_vector_type(8))) short short8;
typedef __attribute__((ext_vector_type(4))) float f32x4;
typedef __attribute__((ext_vector_type(4))) unsigned short ushort4v;

__device__ __forceinline__ bf16_t f2bf(float f) {
    unsigned u = __float_as_uint(f);
    u += 0x7fff + ((u >> 16) & 1);   // round-to-nearest-even
    return (bf16_t)(u >> 16);
}
__device__ __forceinline__ float bf2f(bf16_t b) {
    return __uint_as_float(((unsigned)b) << 16);
}
__device__ __forceinline__ float sigmoidf_(float x) { return 1.0f / (1.0f + expf(-x)); }

// Async global->LDS, 16B per lane. LDS dest = wave-uniform base + lane*16.
__device__ __forceinline__ void stage16(const bf16_t* g, bf16_t* lds_wave_base, int lane) {
#if defined(__has_builtin) && __has_builtin(__builtin_amdgcn_global_load_lds)
    __builtin_amdgcn_global_load_lds(
        (const __attribute__((address_space(1))) void*)g,
        (__attribute__((address_space(3))) void*)lds_wave_base, 16, 0, 0);
#else
    *(short8*)(lds_wave_base + lane * 8) = *(const short8*)g;
#endif
}

// ---------------------------------------------------------------------------
// 128x128-tile bf16 MFMA GEMM, m97 structure.
// MODE 0: C[m*ldc+n] = acc (+bias)               (fp32 out)
// MODE 2: vocab projection. Grid: x = n-tile (padded to 80 = 0 mod 8 so the
//         XCD assignment x%8 is STABLE across m-groups -> each XCD keeps a
//         2.5MB Wout slice L2-resident instead of all XCDs re-fetching all
//         of Wout), y = m-tile (= timestep, since B==128==tile height).
//         lengths sorted desc => valid rows are prefix [0,cnt); skip fully
//         masked 16-row fragments, wave-interleaved (rt = fm*2+wm).
// MODE 3: bf16 out: ((bf16*)C)[m*ldc+n] = bf16(acc)
// ---------------------------------------------------------------------------
template<int MODE>
__global__ __launch_bounds__(256) void mfma_gemm_lds(
    const bf16_t* __restrict__ A, const bf16_t* __restrict__ W,
    const float* __restrict__ bias, const int* __restrict__ lengths,
    float* __restrict__ C, int M, int N, int K, int ldc)
{
    __shared__ __align__(16) bf16_t As[128 * 32];
    __shared__ __align__(16) bf16_t Ws[128 * 32];
    const int tid = threadIdx.x;
    const int wave = tid >> 6, lane = tid & 63;
    const int wm = wave >> 1, wn = wave & 1;
    const int quad = lane >> 4, l16 = lane & 15;
    const int m0 = blockIdx.y * 128;
    const int n0 = blockIdx.x * 128;
    if (MODE == 2 && n0 >= N) return;        // grid.x padded to multiple of 8

    int cnt = 128;
    if constexpr (MODE == 2) {
        const int tt = blockIdx.y;           // m-tile == timestep (B==128)
        cnt = __syncthreads_count(tid < B && lengths[tid] > tt);
    }

    f32x4 acc[4][4];
    #pragma unroll
    for (int i = 0; i < 4; ++i)
        #pragma unroll
        for (int j = 0; j < 4; ++j)
            acc[i][j] = (f32x4){0.f, 0.f, 0.f, 0.f};

    for (int kk = 0; kk < K; kk += 32) {
        #pragma unroll
        for (int i = 0; i < 2; ++i) {
            int c = tid + i * 256;          // chunk 0..511
            int row = c >> 2, seg = c & 3;
            int m = m0 + row; if (m >= M) m = M - 1;
            stage16(A + (size_t)m * K + kk + seg * 8, &As[(i * 256 + wave * 64) * 8], lane);
            int n = n0 + row; if (n >= N) n = N - 1;
            stage16(W + (size_t)n * K + kk + seg * 8, &Ws[(i * 256 + wave * 64) * 8], lane);
        }
        __syncthreads();
        short8 af[4], bfr[4];
        #pragma unroll
        for (int fm = 0; fm < 4; ++fm) {
            const int rt = (MODE == 2) ? fm * 2 + wm : wm * 4 + fm;
            if (MODE != 2 || rt * 16 < cnt)
                af[fm] = *(const short8*)&As[(rt * 16 + l16) * 32 + quad * 8];
        }
        #pragma unroll
        for (int fn = 0; fn < 4; ++fn)
            bfr[fn] = *(const short8*)&Ws[(wn * 64 + fn * 16 + l16) * 32 + quad * 8];
        #pragma unroll
        for (int fm = 0; fm < 4; ++fm) {
            const int rt = (MODE == 2) ? fm * 2 + wm : wm * 4 + fm;
            if (MODE == 2 && rt * 16 >= cnt) continue;
            #pragma unroll
            for (int fn = 0; fn < 4; ++fn)
                acc[fm][fn] = __builtin_amdgcn_mfma_f32_16x16x32_bf16(
                    af[fm], bfr[fn], acc[fm][fn], 0, 0, 0);
        }
        __syncthreads();
    }

    #pragma unroll
    for (int fm = 0; fm < 4; ++fm) {
        const int rt = (MODE == 2) ? fm * 2 + wm : wm * 4 + fm;
        #pragma unroll
        for (int fn = 0; fn < 4; ++fn) {
            #pragma unroll
            for (int r = 0; r < 4; ++r) {
                int m = m0 + rt * 16 + quad * 4 + r;
                int n = n0 + wn * 64 + fn * 16 + l16;
                if (m >= M || n >= N) continue;
                float v = acc[fm][fn][r];
                if (MODE == 0) {
                    if (bias) v += bias[n];
                    C[(size_t)m * ldc + n] = v;
                } else if (MODE == 2) {
                    int t = m >> 7, b = m & 127;
                    v = (t < lengths[b]) ? (v + bias[n]) : 0.f;
                    C[((size_t)b * T + t) * V + n] = v;
                } else {
                    ((bf16_t*)C)[(size_t)m * ldc + n] = f2bf(v);
                }
            }
        }
    }
}

// ---------------------------------------------------------------------------
// ah[b,a] = dot(h[b,:], Wh[a,:]).  Grid (8 b-groups, 8 a-groups).
// Each block stages its 16 h rows (contiguous 64KB fp32) in LDS and streams
// 64 Wh rows once => Wh is read 8x/step total (was 128x when every
// attention block did its own full GEMV).
// ---------------------------------------------------------------------------
__global__ __launch_bounds__(256) void gemv_ah(
    const float* __restrict__ hf, const bf16_t* __restrict__ Wh_bf,
    float* __restrict__ ah)
{
    __shared__ float hs[16 * D];             // 64 KB
    const int tid = threadIdx.x;
    const int bg = blockIdx.x;               // 16 b rows
    const int ag = blockIdx.y;               // 64 a rows
    const float4* src = (const float4*)(hf + (size_t)bg * 16 * D);
    #pragma unroll
    for (int i = 0; i < 16; ++i)
        ((float4*)hs)[i * 256 + tid] = src[i * 256 + tid];
    __syncthreads();

    const int lane = tid & 63, wave = tid >> 6;
    const int a = ag * 64 + lane;
    const bf16_t* wr = Wh_bf + (size_t)a * D;
    const float* h0 = hs + (wave * 4 + 0) * D;
    const float* h1 = hs + (wave * 4 + 1) * D;
    const float* h2 = hs + (wave * 4 + 2) * D;
    const float* h3 = hs + (wave * 4 + 3) * D;
    float s0 = 0.f, s1 = 0.f, s2 = 0.f, s3 = 0.f;
    for (int k = 0; k < D; k += 8) {
        short8 wv = *(const short8*)(wr + k);
        #pragma unroll
        for (int j = 0; j < 8; ++j) {
            float w = bf2f((bf16_t)wv[j]);
            s0 = fmaf(w, h0[k + j], s0);
            s1 = fmaf(w, h1[k + j], s1);
            s2 = fmaf(w, h2[k + j], s2);
            s3 = fmaf(w, h3[k + j], s3);
        }
    }
    const int b = bg * 16 + wave * 4;
    ah[(size_t)(b + 0) * ATT + a] = s0;
    ah[(size_t)(b + 1) * ATT + a] = s1;
    ah[(size_t)(b + 2) * ATT + a] = s2;
    ah[(size_t)(b + 3) * ATT + a] = s3;
}

// ---------------------------------------------------------------------------
// Per-step scores + softmax + P-contraction (ah precomputed by gemv_ah).
// Grid (B, 2): each half-block contracts a 2048-col half of
//   partial[b,:] = sum_r alpha[b,r]*P[b,r,:] + wordsW[t,b,:]
// ---------------------------------------------------------------------------
__global__ __launch_bounds__(256) void att_sc_p(
    const float* __restrict__ ah, const float* __restrict__ att_fea,
    const float* __restrict__ att_bias, const float* __restrict__ Ww,
    const bf16_t* __restrict__ P_bf, const float* __restrict__ wordsW,
    float* __restrict__ partial, int t)
{
    const int b = blockIdx.x, half = blockIdx.y, tid = threadIdx.x;
    __shared__ float ah_s[ATT];
    __shared__ float sc_s[64];
    __shared__ float alpha_s[R];
    const int wave = tid >> 6, lane = tid & 63;

    if (t > 0) {
        if (tid < 128) ((float4*)ah_s)[tid] = ((const float4*)(ah + (size_t)b * ATT))[tid];
        __syncthreads();
        for (int r = wave; r < R; r += 4) {
            float abv = att_bias[r];
            const float* af = att_fea + ((size_t)b * R + r) * ATT;
            float s = 0.f;
            for (int a = lane; a < ATT; a += 64) {
                float v = af[a] + ah_s[a] + abv;
                s = fmaf(fmaxf(v, 0.f), Ww[a], s);
            }
            #pragma unroll
            for (int off = 32; off; off >>= 1) s += __shfl_down(s, off);
            if (lane == 0) sc_s[r] = s;
        }
        __syncthreads();
        if (tid < 64) {
            float v = (tid < R) ? sc_s[tid] : -INFINITY;
            float m = v;
            #pragma unroll
            for (int off = 32; off; off >>= 1) m = fmaxf(m, __shfl_down(m, off));
            m = __shfl(m, 0);
            float e = (tid < R) ? expf(v - m) : 0.f;
            float ss = e;
            #pragma unroll
            for (int off = 32; off; off >>= 1) ss += __shfl_down(ss, off);
            ss = __shfl(ss, 0);
            if (tid < R) alpha_s[tid] = e / ss;
        }
        __syncthreads();
    }

    const int n0c = half * 2048 + tid * 8;
    float acc[8];
    #pragma unroll
    for (int j = 0; j < 8; ++j) acc[j] = 0.f;
    const bf16_t* Pb = P_bf + (size_t)b * R * G4 + n0c;
    #pragma unroll 4
    for (int r = 0; r < R; ++r) {
        float al = (t == 0) ? (1.0f / R) : alpha_s[r];
        short8 p = *(const short8*)(Pb + (size_t)r * G4);
        #pragma unroll
        for (int j = 0; j < 8; ++j)
            acc[j] = fmaf(al, bf2f((bf16_t)p[j]), acc[j]);
    }
    const float* wsl = wordsW + ((size_t)t * B + b) * G4 + n0c;
    float* po = partial + (size_t)b * G4 + n0c;
    float4 w0 = *(const float4*)(wsl);
    float4 w1 = *(const float4*)(wsl + 4);
    float4 o0 = { acc[0] + w0.x, acc[1] + w0.y, acc[2] + w0.z, acc[3] + w0.w };
    float4 o1 = { acc[4] + w1.x, acc[5] + w1.y, acc[6] + w1.z, acc[7] + w1.w };
    *(float4*)(po)     = o0;
    *(float4*)(po + 4) = o1;
}

// ---------------------------------------------------------------------------
// One-shot Whh re-pack: per d-tile (128 of them) a contiguous 64KB slab in
// EXACTLY the LDS layout gates_lstm wants: chunk c = qk*32+row (16B each),
// row = gathered gate-row (g = row>>3, within = row&7), qk = 8-elem k-slot.
// Makes the per-step global_load_lds staging perfectly coalesced.
// ---------------------------------------------------------------------------
__global__ __launch_bounds__(256) void whh_pack_k(
    const bf16_t* __restrict__ Whh, bf16_t* __restrict__ pk)
{
    int idx = blockIdx.x * 256 + threadIdx.x;    // 128*4096 chunks
    int dt = idx >> 12, c = idx & 4095;
    int row = c & 31, qk = c >> 5;
    int rv = (row >> 3) * D + dt * 8 + (row & 7);
    *(short8*)(pk + ((size_t)dt << 15) + (size_t)c * 8) =
        *(const short8*)(Whh + (size_t)rv * D + qk * 8);
}

// ---------------------------------------------------------------------------
// Per-step h-GEMM + LSTM pointwise. Block (d-tile of 8, m-tile of 64).
// Whh slab staged from the packed layout (contiguous 64KB -> full-BW
// global_load_lds), then a barrier-free unrolled K-loop of MFMAs.
// ---------------------------------------------------------------------------
__global__ __launch_bounds__(256) void gates_lstm(
    const bf16_t* __restrict__ h_in,    // B x D bf16 (step t-1)
    const bf16_t* __restrict__ Whh_pk,  // packed slabs
    const float* __restrict__ bih, const float* __restrict__ bhh,
    const float* __restrict__ partial,  // B x G4 (alpha.P + wordsW[t])
    const int* __restrict__ lengths,
    float* __restrict__ c_st,           // B x D fp32 (in/out)
    float* __restrict__ h_f32,          // B x D fp32 (in/out, for attention)
    bf16_t* __restrict__ h_out,         // B x D bf16 (step t)
    bf16_t* __restrict__ hseq,          // (t*B+m)*D
    int t)
{
    __shared__ __align__(16) bf16_t Ws[32 * 1024];   // 64 KB
    const int tid = threadIdx.x;
    const int wave = tid >> 6, lane = tid & 63;
    const int quad = lane >> 4, l16 = lane & 15;
    const int d0 = blockIdx.x * 8;
    const int m0 = blockIdx.y * 64;
    const int gsel_ = l16 >> 3, dr = l16 & 7;

    // ---- coalesced one-shot staging of the packed 64KB slab ----
    const bf16_t* slab = Whh_pk + ((size_t)blockIdx.x << 15);
    #pragma unroll
    for (int i = 0; i < 16; ++i) {
        int c = i * 256 + tid;
        stage16(slab + (size_t)c * 8, &Ws[(i * 256 + wave * 64) * 8], lane);
    }

    const bf16_t* Ar = h_in + (size_t)(m0 + wave * 16 + l16) * D + quad * 8;

    f32x4 acc0 = (f32x4){0.f, 0.f, 0.f, 0.f};
    f32x4 acc1 = (f32x4){0.f, 0.f, 0.f, 0.f};
    __syncthreads();                          // drains vmcnt for global_load_lds

    #pragma unroll 8
    for (int kt = 0; kt < 32; ++kt) {
        short8 af = *(const short8*)(Ar + kt * 32);
        const int cb = (kt * 4 + quad) * 32 * 8;   // element base for (kt,quad)
        short8 b0 = *(const short8*)&Ws[cb + l16 * 8];
        short8 b1 = *(const short8*)&Ws[cb + (16 + l16) * 8];
        acc0 = __builtin_amdgcn_mfma_f32_16x16x32_bf16(af, b0, acc0, 0, 0, 0);
        acc1 = __builtin_amdgcn_mfma_f32_16x16x32_bf16(af, b1, acc1, 0, 0, 0);
    }

    const int d = d0 + dr;
    const int col0 = gsel_ * D + d;
    const int col1 = (2 + gsel_) * D + d;
    const float bia0 = bih[col0] + bhh[col0];
    const float bia1 = bih[col1] + bhh[col1];

    #pragma unroll
    for (int r = 0; r < 4; ++r) {
        int m = m0 + wave * 16 + quad * 4 + r;
        size_t pb = (size_t)m * G4;
        float v0 = acc0[r] + bia0 + partial[pb + col0];
        float v1 = acc1[r] + bia1 + partial[pb + col1];
        float w0 = __shfl_xor(v0, 8);
        float w1 = __shfl_xor(v1, 8);
        float iv, fv, gv, ov;
        if (gsel_ == 0) { iv = v0; gv = v1; fv = w0; ov = w1; }
        else            { fv = v0; ov = v1; iv = w0; gv = w1; }
        float ig = sigmoidf_(iv), fg = sigmoidf_(fv);
        float gg = tanhf(gv),     og = sigmoidf_(ov);
        size_t off = (size_t)m * D + d;
        if (gsel_ == 0) {
            float c_old = c_st[off];
            float h_old = h_f32[off];
            float cn = fmaf(fg, c_old, ig * gg);
            float hn = og * tanhf(cn);
            bool msk = t < lengths[m];
            float cv = msk ? cn : c_old;
            float hv = msk ? hn : h_old;
            c_st[off] = cv;
            h_f32[off] = hv;
            bf16_t hb = f2bf(hv);
            h_out[off] = hb;
            hseq[((size_t)t * B + m) * D + d] = hb;
        }
    }
}

// Strided fp32 -> bf16 cast
__global__ __launch_bounds__(256) void cast_bf16_k(
    const float* __restrict__ src, bf16_t* __restrict__ dst,
    int rows, int cols, int ld)
{
    int idx = blockIdx.x * 256 + threadIdx.x;
    int total = rows * (cols >> 2);
    if (idx >= total) return;
    int cq = cols >> 2;
    int r = idx / cq, c4 = (idx - r * cq) * 4;
    float4 v = *(const float4*)(src + (size_t)r * ld + c4);
    ushort4v o = { f2bf(v.x), f2bf(v.y), f2bf(v.z), f2bf(v.w) };
    *(ushort4v*)(dst + (size_t)r * cols + c4) = o;
}

// words_bf[(t*B+b)*E + :] = bf16(embed_W[captions[b][t]][:])
__global__ __launch_bounds__(128) void embed_k(
    const int* __restrict__ captions, const float* __restrict__ embed_W,
    bf16_t* __restrict__ words_bf)
{
    int bt = blockIdx.x;
    int b = bt / T, t = bt - b * T;
    int tok = captions[b * MAXLEN + t];
    int i = threadIdx.x * 4;
    float4 v = *(const float4*)(embed_W + (size_t)tok * E + i);
    ushort4v o = { f2bf(v.x), f2bf(v.y), f2bf(v.z), f2bf(v.w) };
    *(ushort4v*)(words_bf + ((size_t)t * B + b) * E + i) = o;
}

extern "C" void kernel_launch(void* const* d_in, const int* in_sizes, int n_in,
                              void* d_out, int out_size, void* d_ws, size_t ws_size,
                              hipStream_t stream) {
    const float* visual   = (const float*)d_in[0];
    const float* joint    = (const float*)d_in[1];
    const int*   captions = (const int*)d_in[2];
    const int*   lengths  = (const int*)d_in[3];
    const float* embed_W  = (const float*)d_in[5];
    const float* Wih      = (const float*)d_in[6];
    const float* bih      = (const float*)d_in[7];
    const float* Whh      = (const float*)d_in[8];
    const float* bhh      = (const float*)d_in[9];
    const float* W_init_h = (const float*)d_in[10];
    const float* b_init_h = (const float*)d_in[11];
    const float* W_init_c = (const float*)d_in[12];
    const float* b_init_c = (const float*)d_in[13];
    const float* Wv       = (const float*)d_in[14];
    const float* Wh       = (const float*)d_in[15];
    const float* att_bias = (const float*)d_in[16];
    const float* Ww       = (const float*)d_in[17];
    const float* Wout     = (const float*)d_in[18];
    const float* bout     = (const float*)d_in[19];
    float* out = (float*)d_out;

    // ---- workspace carve-up ----
    char* cur = (char*)d_ws;
    auto alloc = [&](size_t bytes) { char* p = cur; cur += (bytes + 15) & ~size_t(15); return p; };
    float*  att_fea  = (float*)alloc((size_t)B * R * ATT * 4);       // 9.4 MB
    float*  wordsW   = (float*)alloc((size_t)T * B * G4 * 4);        // 39.8 MB
    float*  partial  = (float*)alloc((size_t)B * G4 * 4);            // 2.1 MB
    float*  hf       = (float*)alloc((size_t)B * D * 4);
    float*  c_st     = (float*)alloc((size_t)B * D * 4);
    float*  ah       = (float*)alloc((size_t)B * ATT * 4);           // 256 KB
    bf16_t* words_bf = (bf16_t*)alloc((size_t)T * B * E * 2);
    bf16_t* h_ping0  = (bf16_t*)alloc((size_t)B * D * 2);
    bf16_t* h_ping1  = (bf16_t*)alloc((size_t)B * D * 2);
    bf16_t* hseq_bf  = (bf16_t*)alloc((size_t)T * B * D * 2);        // 5 MB
    bf16_t* P_bf     = (bf16_t*)alloc((size_t)B * R * G4 * 2);       // 37.7 MB
    bf16_t* visual_bf= (bf16_t*)alloc((size_t)B * R * VIS * 2);      // 18.9 MB
    bf16_t* Wv_bf    = (bf16_t*)alloc((size_t)ATT * VIS * 2);
    bf16_t* Wh_bf    = (bf16_t*)alloc((size_t)ATT * D * 2);
    bf16_t* Whh_bf   = (bf16_t*)alloc((size_t)G4 * D * 2);
    bf16_t* Whh_pk   = (bf16_t*)alloc((size_t)G4 * D * 2);           // 8 MB packed
    bf16_t* Wih_v_bf = (bf16_t*)alloc((size_t)G4 * VIS * 2);
    bf16_t* Wih_w_bf = (bf16_t*)alloc((size_t)G4 * E * 2);
    bf16_t* Wout_bf  = (bf16_t*)alloc((size_t)V * D * 2);
    bf16_t* joint_bf = (bf16_t*)alloc((size_t)B * MM * 2);
    bf16_t* Winh_bf  = (bf16_t*)alloc((size_t)D * MM * 2);
    bf16_t* Winc_bf  = (bf16_t*)alloc((size_t)D * MM * 2);

    auto cast = [&](const float* s, bf16_t* dst, int rows, int cols, int ld) {
        int total = rows * (cols >> 2);
        cast_bf16_k<<<(total + 255) / 256, 256, 0, stream>>>(s, dst, rows, cols, ld);
    };
    cast(visual, visual_bf, 1, B * R * VIS, B * R * VIS);
    cast(Wv,  Wv_bf,  ATT, VIS, VIS);
    cast(Wh,  Wh_bf,  ATT, D, D);
    cast(Whh, Whh_bf, G4, D, D);
    cast(Wih, Wih_v_bf, G4, VIS, VIS + E);
    cast(Wih + VIS, Wih_w_bf, G4, E, VIS + E);
    cast(Wout, Wout_bf, V, D, D);
    cast(joint, joint_bf, 1, B * MM, B * MM);
    cast(W_init_h, Winh_bf, 1, D * MM, D * MM);
    cast(W_init_c, Winc_bf, 1, D * MM, D * MM);

    whh_pack_k<<<(128 * 4096) / 256, 256, 0, stream>>>(Whh_bf, Whh_pk);
    embed_k<<<B * T, 128, 0, stream>>>(captions, embed_W, words_bf);

    // h0/c0 seed via MFMA
    mfma_gemm_lds<0><<<dim3(D / 128, B / 128), 256, 0, stream>>>(
        joint_bf, Winh_bf, b_init_h, nullptr, hf, B, D, MM, D);
    mfma_gemm_lds<0><<<dim3(D / 128, B / 128), 256, 0, stream>>>(
        joint_bf, Winc_bf, b_init_c, nullptr, c_st, B, D, MM, D);
    cast(hf, h_ping0, 1, B * D, B * D);

    // att_fea = visual @ Wv^T (fp32 out)
    mfma_gemm_lds<0><<<dim3(ATT / 128, (B * R) / 128), 256, 0, stream>>>(
        visual_bf, Wv_bf, nullptr, nullptr, att_fea, B * R, ATT, VIS, ATT);

    // wordsW = words @ Wih_w^T (all steps)
    mfma_gemm_lds<0><<<dim3(G4 / 128, (T * B) / 128), 256, 0, stream>>>(
        words_bf, Wih_w_bf, nullptr, nullptr, wordsW, T * B, G4, E, G4);

    // P = visual @ Wih_v^T (bf16 out)
    mfma_gemm_lds<3><<<dim3(G4 / 128, (B * R) / 128), 256, 0, stream>>>(
        visual_bf, Wih_v_bf, nullptr, nullptr, (float*)P_bf, B * R, G4, VIS, G4);

    // ---- recurrence (h bf16 ping-pong), 3 lean kernels per step ----
    bf16_t* h_buf[2] = { h_ping0, h_ping1 };
    for (int t = 0; t < T; ++t) {
        if (t > 0)
            gemv_ah<<<dim3(8, 8), 256, 0, stream>>>(hf, Wh_bf, ah);
        att_sc_p<<<dim3(B, 2), 256, 0, stream>>>(
            ah, att_fea, att_bias, Ww, P_bf, wordsW, partial, t);
        gates_lstm<<<dim3(D / 8, B / 64), 256, 0, stream>>>(
            h_buf[t & 1], Whh_pk, bih, bhh, partial, lengths,
            c_st, hf, h_buf[(t + 1) & 1], hseq_bf, t);
    }

    // ---- deferred vocab projection (x = n-tile padded to 80, y = m-tile) ----
    mfma_gemm_lds<2><<<dim3(80, (T * B) / 128), 256, 0, stream>>>(
        hseq_bf, Wout_bf, bout, lengths, out, T * B, V, D, V);
}

// Round 6
// 1268.914 us; speedup vs baseline: 2.1956x; 1.2087x over previous
//
#include <hip/hip_runtime.h>
#include <math.h>

// Problem constants (fixed by reference)
#define B 128
#define R 36
#define VIS 2048
#define MM 1024
#define E 512
#define ATT 512
#define D 1024
#define V 10000
#define MAXLEN 20
#define T 19          // MAXLEN - 1
#define G4 4096       // 4*D

typedef unsigned short bf16_t;
typedef __attribute__((ext_vector_type(8))) short short8;
typedef __attribute__((ext_vector_type(4))) float f32x4;
typedef __attribute__((ext_vector_type(4))) unsigned short ushort4v;

__device__ __forceinline__ bf16_t f2bf(float f) {
    unsigned u = __float_as_uint(f);
    u += 0x7fff + ((u >> 16) & 1);   // round-to-nearest-even
    return (bf16_t)(u >> 16);
}
__device__ __forceinline__ float bf2f(bf16_t b) {
    return __uint_as_float(((unsigned)b) << 16);
}
__device__ __forceinline__ float sigmoidf_(float x) { return 1.0f / (1.0f + expf(-x)); }

// Async global->LDS, 16B per lane. LDS dest = wave-uniform base + lane*16.
__device__ __forceinline__ void stage16(const bf16_t* g, bf16_t* lds_wave_base, int lane) {
#if defined(__has_builtin) && __has_builtin(__builtin_amdgcn_global_load_lds)
    __builtin_amdgcn_global_load_lds(
        (const __attribute__((address_space(1))) void*)g,
        (__attribute__((address_space(3))) void*)lds_wave_base, 16, 0, 0);
#else
    *(short8*)(lds_wave_base + lane * 8) = *(const short8*)g;
#endif
}

// ---------------------------------------------------------------------------
// 128x128-tile bf16 MFMA GEMM, m97 structure.
// MODE 0: C[m*ldc+n] = acc (+bias)               (fp32 out)
// MODE 2: vocab projection. x = n-tile (padded to 80 so XCD = x%8 is stable
//         across m-groups -> per-XCD L2-resident Wout slice), y = m-tile
//         (= timestep). lengths sorted desc => valid rows are prefix
//         [0,cnt); skip staging AND MFMAs for fully-masked 16-row groups.
// MODE 3: bf16 out
// MODE 4: h0/c0 fused init: N=2048; n<D -> hf=v+bias[n] (+bf16 copy to C3);
//         n>=D -> C2=v+bias2[n-D]
// ---------------------------------------------------------------------------
template<int MODE>
__global__ __launch_bounds__(256) void mfma_gemm_lds(
    const bf16_t* __restrict__ A, const bf16_t* __restrict__ W,
    const float* __restrict__ bias, const int* __restrict__ lengths,
    float* __restrict__ C, int M, int N, int K, int ldc,
    const float* __restrict__ bias2, float* __restrict__ C2,
    bf16_t* __restrict__ C3)
{
    __shared__ __align__(16) bf16_t As[128 * 32];
    __shared__ __align__(16) bf16_t Ws[128 * 32];
    const int tid = threadIdx.x;
    const int wave = tid >> 6, lane = tid & 63;
    const int wm = wave >> 1, wn = wave & 1;
    const int quad = lane >> 4, l16 = lane & 15;
    const int m0 = blockIdx.y * 128;
    const int n0 = blockIdx.x * 128;
    if (MODE == 2 && n0 >= N) return;        // grid.x padded to multiple of 8

    int cnt = 128;
    if constexpr (MODE == 2) {
        const int tt = blockIdx.y;           // m-tile == timestep (B==128)
        cnt = __syncthreads_count(tid < B && lengths[tid] > tt);
    }

    f32x4 acc[4][4];
    #pragma unroll
    for (int i = 0; i < 4; ++i)
        #pragma unroll
        for (int j = 0; j < 4; ++j)
            acc[i][j] = (f32x4){0.f, 0.f, 0.f, 0.f};

    for (int kk = 0; kk < K; kk += 32) {
        #pragma unroll
        for (int i = 0; i < 2; ++i) {
            int c = tid + i * 256;          // chunk 0..511
            int row = c >> 2, seg = c & 3;
            if (MODE != 2 || (i * 64 + wave * 16) < cnt) {   // wave-uniform skip
                int m = m0 + row; if (m >= M) m = M - 1;
                stage16(A + (size_t)m * K + kk + seg * 8, &As[(i * 256 + wave * 64) * 8], lane);
            }
            int n = n0 + row; if (n >= N) n = N - 1;
            stage16(W + (size_t)n * K + kk + seg * 8, &Ws[(i * 256 + wave * 64) * 8], lane);
        }
        __syncthreads();
        short8 af[4], bfr[4];
        #pragma unroll
        for (int fm = 0; fm < 4; ++fm) {
            const int rt = (MODE == 2) ? fm * 2 + wm : wm * 4 + fm;
            if (MODE != 2 || rt * 16 < cnt)
                af[fm] = *(const short8*)&As[(rt * 16 + l16) * 32 + quad * 8];
        }
        #pragma unroll
        for (int fn = 0; fn < 4; ++fn)
            bfr[fn] = *(const short8*)&Ws[(wn * 64 + fn * 16 + l16) * 32 + quad * 8];
        #pragma unroll
        for (int fm = 0; fm < 4; ++fm) {
            const int rt = (MODE == 2) ? fm * 2 + wm : wm * 4 + fm;
            if (MODE == 2 && rt * 16 >= cnt) continue;
            #pragma unroll
            for (int fn = 0; fn < 4; ++fn)
                acc[fm][fn] = __builtin_amdgcn_mfma_f32_16x16x32_bf16(
                    af[fm], bfr[fn], acc[fm][fn], 0, 0, 0);
        }
        __syncthreads();
    }

    #pragma unroll
    for (int fm = 0; fm < 4; ++fm) {
        const int rt = (MODE == 2) ? fm * 2 + wm : wm * 4 + fm;
        #pragma unroll
        for (int fn = 0; fn < 4; ++fn) {
            #pragma unroll
            for (int r = 0; r < 4; ++r) {
                int m = m0 + rt * 16 + quad * 4 + r;
                int n = n0 + wn * 64 + fn * 16 + l16;
                if (m >= M || n >= N) continue;
                float v = acc[fm][fn][r];
                if (MODE == 0) {
                    if (bias) v += bias[n];
                    C[(size_t)m * ldc + n] = v;
                } else if (MODE == 2) {
                    int t = m >> 7, b = m & 127;
                    v = (t < lengths[b]) ? (v + bias[n]) : 0.f;
                    C[((size_t)b * T + t) * V + n] = v;
                } else if (MODE == 4) {
                    if (n < D) {
                        float v2 = v + bias[n];
                        C[(size_t)m * D + n] = v2;
                        C3[(size_t)m * D + n] = f2bf(v2);
                    } else {
                        C2[(size_t)m * D + (n - D)] = v + bias2[n - D];
                    }
                } else {
                    ((bf16_t*)C)[(size_t)m * ldc + n] = f2bf(v);
                }
            }
        }
    }
}

// ---------------------------------------------------------------------------
// MFMA ah-GEMM: ah[m, a0:a0+32] for 64 m-rows per block, gates_lstm
// structure (packed 32-row Wh slab -> LDS once, barrier-free MFMA K-loop).
// Replaces the LDS-issue-bound scalar GEMV (32 ds_read_b32 per 32 FMAs).
// Grid (ATT/32 = 16, B/64 = 2).
// ---------------------------------------------------------------------------
__global__ __launch_bounds__(256) void mfma_ah(
    const bf16_t* __restrict__ h_in,    // B x D bf16 (step t-1)
    const bf16_t* __restrict__ Wh_pk,   // packed slabs (16 x 64KB)
    float* __restrict__ ah)
{
    __shared__ __align__(16) bf16_t Ws[32 * 1024];   // 64 KB
    const int tid = threadIdx.x;
    const int wave = tid >> 6, lane = tid & 63;
    const int quad = lane >> 4, l16 = lane & 15;
    const int a0 = blockIdx.x * 32;
    const int m0 = blockIdx.y * 64;

    const bf16_t* slab = Wh_pk + ((size_t)blockIdx.x << 15);
    #pragma unroll
    for (int i = 0; i < 16; ++i) {
        int c = i * 256 + tid;
        stage16(slab + (size_t)c * 8, &Ws[(i * 256 + wave * 64) * 8], lane);
    }
    const bf16_t* Ar = h_in + (size_t)(m0 + wave * 16 + l16) * D + quad * 8;
    f32x4 acc0 = (f32x4){0.f, 0.f, 0.f, 0.f};
    f32x4 acc1 = (f32x4){0.f, 0.f, 0.f, 0.f};
    __syncthreads();

    #pragma unroll 8
    for (int kt = 0; kt < 32; ++kt) {
        short8 af = *(const short8*)(Ar + kt * 32);
        const int cb = (kt * 4 + quad) * 32 * 8;
        short8 b0 = *(const short8*)&Ws[cb + l16 * 8];
        short8 b1 = *(const short8*)&Ws[cb + (16 + l16) * 8];
        acc0 = __builtin_amdgcn_mfma_f32_16x16x32_bf16(af, b0, acc0, 0, 0, 0);
        acc1 = __builtin_amdgcn_mfma_f32_16x16x32_bf16(af, b1, acc1, 0, 0, 0);
    }
    #pragma unroll
    for (int r = 0; r < 4; ++r) {
        int m = m0 + wave * 16 + quad * 4 + r;
        ah[(size_t)m * ATT + a0 + l16]      = acc0[r];
        ah[(size_t)m * ATT + a0 + 16 + l16] = acc1[r];
    }
}

// ---------------------------------------------------------------------------
// Per-step scores + softmax + P-contraction (ah precomputed by mfma_ah).
// Grid (B, 2): each half-block contracts a 2048-col half of
//   partial[b,:] = sum_r alpha[b,r]*P[b,r,:] + wordsW[t,b,:]
// ---------------------------------------------------------------------------
__global__ __launch_bounds__(256) void att_sc_p(
    const float* __restrict__ ah, const float* __restrict__ att_fea,
    const float* __restrict__ att_bias, const float* __restrict__ Ww,
    const bf16_t* __restrict__ P_bf, const float* __restrict__ wordsW,
    float* __restrict__ partial, int t)
{
    const int b = blockIdx.x, half = blockIdx.y, tid = threadIdx.x;
    __shared__ float ah_s[ATT];
    __shared__ float sc_s[64];
    __shared__ float alpha_s[R];
    const int wave = tid >> 6, lane = tid & 63;

    if (t > 0) {
        if (tid < 128) ((float4*)ah_s)[tid] = ((const float4*)(ah + (size_t)b * ATT))[tid];
        __syncthreads();
        for (int r = wave; r < R; r += 4) {
            float abv = att_bias[r];
            const float* af = att_fea + ((size_t)b * R + r) * ATT;
            float s = 0.f;
            for (int a = lane; a < ATT; a += 64) {
                float v = af[a] + ah_s[a] + abv;
                s = fmaf(fmaxf(v, 0.f), Ww[a], s);
            }
            #pragma unroll
            for (int off = 32; off; off >>= 1) s += __shfl_down(s, off);
            if (lane == 0) sc_s[r] = s;
        }
        __syncthreads();
        if (tid < 64) {
            float v = (tid < R) ? sc_s[tid] : -INFINITY;
            float m = v;
            #pragma unroll
            for (int off = 32; off; off >>= 1) m = fmaxf(m, __shfl_down(m, off));
            m = __shfl(m, 0);
            float e = (tid < R) ? expf(v - m) : 0.f;
            float ss = e;
            #pragma unroll
            for (int off = 32; off; off >>= 1) ss += __shfl_down(ss, off);
            ss = __shfl(ss, 0);
            if (tid < R) alpha_s[tid] = e / ss;
        }
        __syncthreads();
    }

    const int n0c = half * 2048 + tid * 8;
    float acc[8];
    #pragma unroll
    for (int j = 0; j < 8; ++j) acc[j] = 0.f;
    const bf16_t* Pb = P_bf + (size_t)b * R * G4 + n0c;
    #pragma unroll 4
    for (int r = 0; r < R; ++r) {
        float al = (t == 0) ? (1.0f / R) : alpha_s[r];
        short8 p = *(const short8*)(Pb + (size_t)r * G4);
        #pragma unroll
        for (int j = 0; j < 8; ++j)
            acc[j] = fmaf(al, bf2f((bf16_t)p[j]), acc[j]);
    }
    const float* wsl = wordsW + ((size_t)t * B + b) * G4 + n0c;
    float* po = partial + (size_t)b * G4 + n0c;
    float4 w0 = *(const float4*)(wsl);
    float4 w1 = *(const float4*)(wsl + 4);
    float4 o0 = { acc[0] + w0.x, acc[1] + w0.y, acc[2] + w0.z, acc[3] + w0.w };
    float4 o1 = { acc[4] + w1.x, acc[5] + w1.y, acc[6] + w1.z, acc[7] + w1.w };
    *(float4*)(po)     = o0;
    *(float4*)(po + 4) = o1;
}

// ---------------------------------------------------------------------------
// One-shot Whh re-pack: per d-tile a contiguous 64KB slab in EXACTLY the
// LDS layout gates_lstm wants (chunk c = qk*32+row; row = gathered gate-row).
// ---------------------------------------------------------------------------
__global__ __launch_bounds__(256) void whh_pack_k(
    const bf16_t* __restrict__ Whh, bf16_t* __restrict__ pk)
{
    int idx = blockIdx.x * 256 + threadIdx.x;    // 128*4096 chunks
    int dt = idx >> 12, c = idx & 4095;
    int row = c & 31, qk = c >> 5;
    int rv = (row >> 3) * D + dt * 8 + (row & 7);
    *(short8*)(pk + ((size_t)dt << 15) + (size_t)c * 8) =
        *(const short8*)(Whh + (size_t)rv * D + qk * 8);
}

// One-shot Wh re-pack for mfma_ah: a-tile at owns rows at*32..+32 (no gather).
__global__ __launch_bounds__(256) void wh_pack_k(
    const bf16_t* __restrict__ Wh, bf16_t* __restrict__ pk)
{
    int idx = blockIdx.x * 256 + threadIdx.x;    // 16*4096 chunks
    int at = idx >> 12, c = idx & 4095;
    int row = c & 31, qk = c >> 5;
    *(short8*)(pk + ((size_t)at << 15) + (size_t)c * 8) =
        *(const short8*)(Wh + (size_t)(at * 32 + row) * D + qk * 8);
}

// ---------------------------------------------------------------------------
// Per-step h-GEMM + LSTM pointwise. Block (d-tile of 8, m-tile of 64).
// ---------------------------------------------------------------------------
__global__ __launch_bounds__(256) void gates_lstm(
    const bf16_t* __restrict__ h_in,    // B x D bf16 (step t-1)
    const bf16_t* __restrict__ Whh_pk,  // packed slabs
    const float* __restrict__ bih, const float* __restrict__ bhh,
    const float* __restrict__ partial,  // B x G4 (alpha.P + wordsW[t])
    const int* __restrict__ lengths,
    float* __restrict__ c_st,           // B x D fp32 (in/out)
    float* __restrict__ h_f32,          // B x D fp32 (in/out)
    bf16_t* __restrict__ h_out,         // B x D bf16 (step t)
    bf16_t* __restrict__ hseq,          // (t*B+m)*D
    int t)
{
    __shared__ __align__(16) bf16_t Ws[32 * 1024];   // 64 KB
    const int tid = threadIdx.x;
    const int wave = tid >> 6, lane = tid & 63;
    const int quad = lane >> 4, l16 = lane & 15;
    const int d0 = blockIdx.x * 8;
    const int m0 = blockIdx.y * 64;
    const int gsel_ = l16 >> 3, dr = l16 & 7;

    const bf16_t* slab = Whh_pk + ((size_t)blockIdx.x << 15);
    #pragma unroll
    for (int i = 0; i < 16; ++i) {
        int c = i * 256 + tid;
        stage16(slab + (size_t)c * 8, &Ws[(i * 256 + wave * 64) * 8], lane);
    }

    const bf16_t* Ar = h_in + (size_t)(m0 + wave * 16 + l16) * D + quad * 8;

    f32x4 acc0 = (f32x4){0.f, 0.f, 0.f, 0.f};
    f32x4 acc1 = (f32x4){0.f, 0.f, 0.f, 0.f};
    __syncthreads();                          // drains vmcnt for global_load_lds

    #pragma unroll 8
    for (int kt = 0; kt < 32; ++kt) {
        short8 af = *(const short8*)(Ar + kt * 32);
        const int cb = (kt * 4 + quad) * 32 * 8;   // element base for (kt,quad)
        short8 b0 = *(const short8*)&Ws[cb + l16 * 8];
        short8 b1 = *(const short8*)&Ws[cb + (16 + l16) * 8];
        acc0 = __builtin_amdgcn_mfma_f32_16x16x32_bf16(af, b0, acc0, 0, 0, 0);
        acc1 = __builtin_amdgcn_mfma_f32_16x16x32_bf16(af, b1, acc1, 0, 0, 0);
    }

    const int d = d0 + dr;
    const int col0 = gsel_ * D + d;
    const int col1 = (2 + gsel_) * D + d;
    const float bia0 = bih[col0] + bhh[col0];
    const float bia1 = bih[col1] + bhh[col1];

    #pragma unroll
    for (int r = 0; r < 4; ++r) {
        int m = m0 + wave * 16 + quad * 4 + r;
        size_t pb = (size_t)m * G4;
        float v0 = acc0[r] + bia0 + partial[pb + col0];
        float v1 = acc1[r] + bia1 + partial[pb + col1];
        float w0 = __shfl_xor(v0, 8);
        float w1 = __shfl_xor(v1, 8);
        float iv, fv, gv, ov;
        if (gsel_ == 0) { iv = v0; gv = v1; fv = w0; ov = w1; }
        else            { fv = v0; ov = v1; iv = w0; gv = w1; }
        float ig = sigmoidf_(iv), fg = sigmoidf_(fv);
        float gg = tanhf(gv),     og = sigmoidf_(ov);
        size_t off = (size_t)m * D + d;
        if (gsel_ == 0) {
            float c_old = c_st[off];
            float h_old = h_f32[off];
            float cn = fmaf(fg, c_old, ig * gg);
            float hn = og * tanhf(cn);
            bool msk = t < lengths[m];
            float cv = msk ? cn : c_old;
            float hv = msk ? hn : h_old;
            c_st[off] = cv;
            h_f32[off] = hv;
            bf16_t hb = f2bf(hv);
            h_out[off] = hb;
            hseq[((size_t)t * B + m) * D + d] = hb;
        }
    }
}

// ---------------------------------------------------------------------------
// Fused bf16 cast: all 10 weight/activation casts in ONE dispatch.
// ---------------------------------------------------------------------------
struct CastSeg { const float* s; bf16_t* d; int cols; int ld; int total4; int blk0; };
struct Cast10 { CastSeg g[10]; };

__global__ __launch_bounds__(256) void fused_cast_k(Cast10 a)
{
    const int bx = blockIdx.x;
    CastSeg sg = a.g[0];
    #pragma unroll
    for (int j = 1; j < 10; ++j) if (bx >= a.g[j].blk0) sg = a.g[j];
    int idx = (bx - sg.blk0) * 256 + threadIdx.x;
    if (idx >= sg.total4) return;
    int cq = sg.cols >> 2;
    int r = idx / cq, c4 = (idx - r * cq) * 4;
    float4 v = *(const float4*)(sg.s + (size_t)r * sg.ld + c4);
    ushort4v o = { f2bf(v.x), f2bf(v.y), f2bf(v.z), f2bf(v.w) };
    *(ushort4v*)(sg.d + (size_t)r * sg.cols + c4) = o;
}

// words_bf[(t*B+b)*E + :] = bf16(embed_W[captions[b][t]][:])
__global__ __launch_bounds__(128) void embed_k(
    const int* __restrict__ captions, const float* __restrict__ embed_W,
    bf16_t* __restrict__ words_bf)
{
    int bt = blockIdx.x;
    int b = bt / T, t = bt - b * T;
    int tok = captions[b * MAXLEN + t];
    int i = threadIdx.x * 4;
    float4 v = *(const float4*)(embed_W + (size_t)tok * E + i);
    ushort4v o = { f2bf(v.x), f2bf(v.y), f2bf(v.z), f2bf(v.w) };
    *(ushort4v*)(words_bf + ((size_t)t * B + b) * E + i) = o;
}

extern "C" void kernel_launch(void* const* d_in, const int* in_sizes, int n_in,
                              void* d_out, int out_size, void* d_ws, size_t ws_size,
                              hipStream_t stream) {
    const float* visual   = (const float*)d_in[0];
    const float* joint    = (const float*)d_in[1];
    const int*   captions = (const int*)d_in[2];
    const int*   lengths  = (const int*)d_in[3];
    const float* embed_W  = (const float*)d_in[5];
    const float* Wih      = (const float*)d_in[6];
    const float* bih      = (const float*)d_in[7];
    const float* Whh      = (const float*)d_in[8];
    const float* bhh      = (const float*)d_in[9];
    const float* W_init_h = (const float*)d_in[10];
    const float* b_init_h = (const float*)d_in[11];
    const float* W_init_c = (const float*)d_in[12];
    const float* b_init_c = (const float*)d_in[13];
    const float* Wv       = (const float*)d_in[14];
    const float* Wh       = (const float*)d_in[15];
    const float* att_bias = (const float*)d_in[16];
    const float* Ww       = (const float*)d_in[17];
    const float* Wout     = (const float*)d_in[18];
    const float* bout     = (const float*)d_in[19];
    float* out = (float*)d_out;

    // ---- workspace carve-up ----
    char* cur = (char*)d_ws;
    auto alloc = [&](size_t bytes) { char* p = cur; cur += (bytes + 15) & ~size_t(15); return p; };
    float*  att_fea  = (float*)alloc((size_t)B * R * ATT * 4);       // 9.4 MB
    float*  wordsW   = (float*)alloc((size_t)T * B * G4 * 4);        // 39.8 MB
    float*  partial  = (float*)alloc((size_t)B * G4 * 4);            // 2.1 MB
    float*  hf       = (float*)alloc((size_t)B * D * 4);
    float*  c_st     = (float*)alloc((size_t)B * D * 4);
    float*  ah       = (float*)alloc((size_t)B * ATT * 4);           // 256 KB
    bf16_t* words_bf = (bf16_t*)alloc((size_t)T * B * E * 2);
    bf16_t* h_ping0  = (bf16_t*)alloc((size_t)B * D * 2);
    bf16_t* h_ping1  = (bf16_t*)alloc((size_t)B * D * 2);
    bf16_t* hseq_bf  = (bf16_t*)alloc((size_t)T * B * D * 2);        // 5 MB
    bf16_t* P_bf     = (bf16_t*)alloc((size_t)B * R * G4 * 2);       // 37.7 MB
    bf16_t* visual_bf= (bf16_t*)alloc((size_t)B * R * VIS * 2);      // 18.9 MB
    bf16_t* Wv_bf    = (bf16_t*)alloc((size_t)ATT * VIS * 2);
    bf16_t* Wh_bf    = (bf16_t*)alloc((size_t)ATT * D * 2);
    bf16_t* Wh_pk    = (bf16_t*)alloc((size_t)ATT * D * 2);          // 1 MB packed
    bf16_t* Whh_bf   = (bf16_t*)alloc((size_t)G4 * D * 2);
    bf16_t* Whh_pk   = (bf16_t*)alloc((size_t)G4 * D * 2);           // 8 MB packed
    bf16_t* Wih_v_bf = (bf16_t*)alloc((size_t)G4 * VIS * 2);
    bf16_t* Wih_w_bf = (bf16_t*)alloc((size_t)G4 * E * 2);
    bf16_t* Wout_bf  = (bf16_t*)alloc((size_t)V * D * 2);
    bf16_t* joint_bf = (bf16_t*)alloc((size_t)B * MM * 2);
    bf16_t* Winit_bf = (bf16_t*)alloc((size_t)2 * D * MM * 2);       // stacked Wh0;Wc0

    // ---- single fused cast dispatch ----
    Cast10 ca;
    int cum = 0;
    auto seg = [&](int i, const float* s, bf16_t* d, int rows, int cols, int ld) {
        int t4 = rows * (cols >> 2);
        ca.g[i] = { s, d, cols, ld, t4, cum };
        cum += (t4 + 255) / 256;
    };
    seg(0, visual, visual_bf, 1, B * R * VIS, B * R * VIS);
    seg(1, Wv,  Wv_bf,  ATT, VIS, VIS);
    seg(2, Wh,  Wh_bf,  ATT, D, D);
    seg(3, Whh, Whh_bf, G4, D, D);
    seg(4, Wih, Wih_v_bf, G4, VIS, VIS + E);
    seg(5, Wih + VIS, Wih_w_bf, G4, E, VIS + E);
    seg(6, Wout, Wout_bf, V, D, D);
    seg(7, joint, joint_bf, 1, B * MM, B * MM);
    seg(8, W_init_h, Winit_bf, 1, D * MM, D * MM);
    seg(9, W_init_c, Winit_bf + (size_t)D * MM, 1, D * MM, D * MM);
    fused_cast_k<<<cum, 256, 0, stream>>>(ca);

    whh_pack_k<<<(128 * 4096) / 256, 256, 0, stream>>>(Whh_bf, Whh_pk);
    wh_pack_k<<<(16 * 4096) / 256, 256, 0, stream>>>(Wh_bf, Wh_pk);
    embed_k<<<B * T, 128, 0, stream>>>(captions, embed_W, words_bf);

    // h0/c0 fused init (MODE 4): one GEMM, bf16 h0 written in epilogue
    mfma_gemm_lds<4><<<dim3(16, 1), 256, 0, stream>>>(
        joint_bf, Winit_bf, b_init_h, nullptr, hf, B, 2 * D, MM, D,
        b_init_c, c_st, h_ping0);

    // att_fea = visual @ Wv^T (fp32 out)
    mfma_gemm_lds<0><<<dim3(ATT / 128, (B * R) / 128), 256, 0, stream>>>(
        visual_bf, Wv_bf, nullptr, nullptr, att_fea, B * R, ATT, VIS, ATT,
        nullptr, nullptr, nullptr);

    // wordsW = words @ Wih_w^T (all steps)
    mfma_gemm_lds<0><<<dim3(G4 / 128, (T * B) / 128), 256, 0, stream>>>(
        words_bf, Wih_w_bf, nullptr, nullptr, wordsW, T * B, G4, E, G4,
        nullptr, nullptr, nullptr);

    // P = visual @ Wih_v^T (bf16 out)
    mfma_gemm_lds<3><<<dim3(G4 / 128, (B * R) / 128), 256, 0, stream>>>(
        visual_bf, Wih_v_bf, nullptr, nullptr, (float*)P_bf, B * R, G4, VIS, G4,
        nullptr, nullptr, nullptr);

    // ---- recurrence (h bf16 ping-pong), 3 lean kernels per step ----
    bf16_t* h_buf[2] = { h_ping0, h_ping1 };
    for (int t = 0; t < T; ++t) {
        if (t > 0)
            mfma_ah<<<dim3(ATT / 32, B / 64), 256, 0, stream>>>(
                h_buf[t & 1], Wh_pk, ah);
        att_sc_p<<<dim3(B, 2), 256, 0, stream>>>(
            ah, att_fea, att_bias, Ww, P_bf, wordsW, partial, t);
        gates_lstm<<<dim3(D / 8, B / 64), 256, 0, stream>>>(
            h_buf[t & 1], Whh_pk, bih, bhh, partial, lengths,
            c_st, hf, h_buf[(t + 1) & 1], hseq_bf, t);
    }

    // ---- deferred vocab projection (x = n-tile padded to 80, y = m-tile) ----
    mfma_gemm_lds<2><<<dim3(80, (T * B) / 128), 256, 0, stream>>>(
        hseq_bf, Wout_bf, bout, lengths, out, T * B, V, D, V,
        nullptr, nullptr, nullptr);
}